// Round 1
// baseline (1343.331 us; speedup 1.0000x reference)
//
#include <hip/hip_runtime.h>
#include <hip/hip_bf16.h>

// Problem: B=64, n=SIZE_IN=1024, m=SIZE_OUT=1024.
// Inputs:  [0] mu_in (64,1024) f32   [1] sigma_in (64,1024,1024) f32
//          [2] w_mu (1024,1024) f32 [i][o]   [3] w_sigma (1024,1024) f32 [o][i]
//          [4] b_mu (1024,1) f32    [5] b_sigma (1024,) f32
// Outputs (flat concat, f32): mu_out (65536) | Sigma_out (67108864) | w_kl | b_kl

typedef short bf16x8 __attribute__((ext_vector_type(8)));
typedef float f32x4  __attribute__((ext_vector_type(4)));

#define LDT 72  // padded LDS leading dim (elements); 144B rows keep 16B alignment

__device__ __forceinline__ unsigned short f2bf(float f) {
    union { float f; unsigned u; } a; a.f = f;
    unsigned u = a.u;
    u += 0x7fffu + ((u >> 16) & 1u);   // round-to-nearest-even
    return (unsigned short)(u >> 16);
}

__device__ __forceinline__ float softplus_eps(float x) {
    return fmaxf(x, 0.f) + log1pf(expf(-fabsf(x))) + 1e-6f;
}

// ---------------- small kernels ----------------

__global__ void k_zero(float* acc) {
    if (threadIdx.x < 16) acc[threadIdx.x] = 0.f;
}

// transpose w_mu [i][o] -> wT [o][i] (f32 + bf16); accumulate sum(w_mu^2) -> acc[1]
__global__ void k_transpose(const float* __restrict__ wmu, float* __restrict__ wT32,
                            unsigned short* __restrict__ wTb, float* __restrict__ acc) {
    __shared__ float tile[64][65];
    const int bx = blockIdx.x;   // i-tile
    const int by = blockIdx.y;   // o-tile
    const int t = threadIdx.x;
    const int r = t >> 4;            // 0..15
    const int c4 = (t & 15) * 4;     // 0..60
    float s = 0.f;
#pragma unroll
    for (int p = 0; p < 4; ++p) {
        const int row = r + p * 16;
        const float4 v = *(const float4*)(wmu + (size_t)(bx * 64 + row) * 1024 + by * 64 + c4);
        tile[row][c4 + 0] = v.x; tile[row][c4 + 1] = v.y;
        tile[row][c4 + 2] = v.z; tile[row][c4 + 3] = v.w;
        s += v.x * v.x + v.y * v.y + v.z * v.z + v.w * v.w;
    }
    __syncthreads();
#pragma unroll
    for (int p = 0; p < 4; ++p) {
        const int row = r + p * 16;  // local o index
        float4 o;
        o.x = tile[c4 + 0][row]; o.y = tile[c4 + 1][row];
        o.z = tile[c4 + 2][row]; o.w = tile[c4 + 3][row];
        const size_t off = (size_t)(by * 64 + row) * 1024 + bx * 64 + c4;
        *(float4*)(wT32 + off) = o;
        ushort4 h; h.x = f2bf(o.x); h.y = f2bf(o.y); h.z = f2bf(o.z); h.w = f2bf(o.w);
        *(ushort4*)(wTb + off) = h;
    }
#pragma unroll
    for (int off = 32; off; off >>= 1) s += __shfl_down(s, off, 64);
    if ((t & 63) == 0) atomicAdd(acc + 1, s);
}

// W_Sig = softplus(w_sigma)+1e-6 (store f32); accumulate sum(W_Sig)->acc[0], sum(log W_Sig)->acc[2]
__global__ void k_wsig(const float* __restrict__ wsg, float* __restrict__ WSig,
                       float* __restrict__ acc) {
    const int idx = (blockIdx.x * 256 + threadIdx.x) * 4;
    const float4 x = *(const float4*)(wsg + idx);
    float4 w;
    w.x = softplus_eps(x.x); w.y = softplus_eps(x.y);
    w.z = softplus_eps(x.z); w.w = softplus_eps(x.w);
    *(float4*)(WSig + idx) = w;
    float sw = w.x + w.y + w.z + w.w;
    float sl = logf(w.x) + logf(w.y) + logf(w.z) + logf(w.w);
#pragma unroll
    for (int off = 32; off; off >>= 1) {
        sw += __shfl_down(sw, off, 64);
        sl += __shfl_down(sl, off, 64);
    }
    if ((threadIdx.x & 63) == 0) { atomicAdd(acc + 0, sw); atomicAdd(acc + 2, sl); }
}

// faithful replication of the torch .view bug: dr[k*64+q] = sigma.flat[k*65600 + q]
__global__ void k_gather(const float* __restrict__ sig, float* __restrict__ dr) {
    const int tg = blockIdx.x * 256 + threadIdx.x;   // 65536 threads
    const int k = tg >> 6, q = tg & 63;
    dr[tg] = sig[(size_t)k * 65600 + q];
}

// mu_out + diag_term (trW + quad + B_Sig)
__global__ void k_small(const float* __restrict__ mu_in, const float* __restrict__ wT32,
                        const float* __restrict__ WSig, const float* __restrict__ dr,
                        const float* __restrict__ b_mu, const float* __restrict__ b_sig,
                        float* __restrict__ mu_out, float* __restrict__ dterm) {
    __shared__ float mu_s[1024];
    __shared__ float m2_s[1024];
    const int blk = blockIdx.x;
    const int b = blk >> 2;
    const int o0 = (blk & 3) * 256;
    const int t = threadIdx.x;
    const int o = o0 + t;
    for (int j = t; j < 1024; j += 256) {
        const float v = mu_in[b * 1024 + j];
        mu_s[j] = v; m2_s[j] = v * v;
    }
    __syncthreads();
    const int rowTr = b * 16 + (o >> 6);
    const int qq = o & 63;
    const float* wrow = wT32 + (size_t)o * 1024;
    const float* srow = WSig + (size_t)o * 1024;
    const float* trow = WSig + (size_t)rowTr * 1024;
    float am = 0.f, aq = 0.f, at = 0.f;
#pragma unroll 4
    for (int i = 0; i < 1024; i += 4) {
        const float4 wv = *(const float4*)(wrow + i);
        const float4 sv = *(const float4*)(srow + i);
        const float4 tv = *(const float4*)(trow + i);
        const float4 mv = *(const float4*)(&mu_s[i]);
        const float4 m2 = *(const float4*)(&m2_s[i]);
        am += wv.x * mv.x + wv.y * mv.y + wv.z * mv.z + wv.w * mv.w;
        aq += sv.x * m2.x + sv.y * m2.y + sv.z * m2.z + sv.w * m2.w;
        at += tv.x * dr[(i + 0) * 64 + qq] + tv.y * dr[(i + 1) * 64 + qq]
            + tv.z * dr[(i + 2) * 64 + qq] + tv.w * dr[(i + 3) * 64 + qq];
    }
    const float bs = softplus_eps(b_sig[o]);
    dterm[b * 1024 + o] = at + aq + bs;
    mu_out[b * 1024 + o] = am + b_mu[o];
}

// b_kl + finalize w_kl from accumulators
__global__ void k_final(const float* __restrict__ b_mu, const float* __restrict__ b_sig,
                        const float* __restrict__ acc, float* __restrict__ out) {
    __shared__ float red[3][4];
    const int t = threadIdx.x, lane = t & 63, w = t >> 6;
    float s1 = 0.f, s2 = 0.f, s3 = 0.f;
    for (int i = t; i < 1024; i += 256) {
        const float sp = softplus_eps(b_sig[i]);
        s1 += sp; s2 += logf(sp);
        const float bm = b_mu[i]; s3 += bm * bm;
    }
#pragma unroll
    for (int off = 32; off; off >>= 1) {
        s1 += __shfl_down(s1, off, 64);
        s2 += __shfl_down(s2, off, 64);
        s3 += __shfl_down(s3, off, 64);
    }
    if (lane == 0) { red[0][w] = s1; red[1][w] = s2; red[2][w] = s3; }
    __syncthreads();
    if (t == 0) {
        const float S1 = red[0][0] + red[0][1] + red[0][2] + red[0][3];
        const float S2 = red[1][0] + red[1][1] + red[1][2] + red[1][3];
        const float S3 = red[2][0] + red[2][1] + red[2][2] + red[2][3];
        out[67174401] = 0.5f * (S1 + S3 - 1024.f - S2);                      // b_kl
        out[67174400] = 0.5f * (acc[0] + acc[1] - 1048576.f - acc[2]);       // w_kl
    }
}

// ---------------- main GEMMs ----------------
// Stage A: T'[b][p][i] = (Sigma_b @ w_mu)[i][p], bf16, transposed store.
//   A-tile = Sigma rows (f32 -> bf16 inline), Bt-tile = wT rows (K-contiguous).
__global__ __launch_bounds__(256, 3) void k_gemmA(const float* __restrict__ sig,
                                                  const unsigned short* __restrict__ wT,
                                                  unsigned short* __restrict__ Tp) {
    __shared__ unsigned short As[128 * LDT];
    __shared__ unsigned short Bs[128 * LDT];
    const int bx = blockIdx.x;   // p-tile
    const int by = blockIdx.y;   // i-tile
    const int bz = blockIdx.z;   // batch
    const int t = threadIdx.x;
    const int lane = t & 63, wave = t >> 6;
    const int wm = wave & 1, wn = wave >> 1;
    const int q = lane >> 4, r = lane & 15;
    const float* Ab = sig + ((size_t)bz << 20) + (size_t)(by * 128) * 1024;
    const unsigned short* Bb = wT + (size_t)(bx * 128) * 1024;
    f32x4 acc[4][4];
#pragma unroll
    for (int a = 0; a < 4; ++a)
#pragma unroll
        for (int b2 = 0; b2 < 4; ++b2) acc[a][b2] = (f32x4){0.f, 0.f, 0.f, 0.f};
    const int arow = t >> 4, acol = (t & 15) * 4;   // A staging: 16 rows/pass x 8
    const int brow = t >> 3, bcol = (t & 7) * 8;    // B staging: 32 rows/pass x 4
    for (int kt = 0; kt < 16; ++kt) {
        const int k0 = kt * 64;
        __syncthreads();
#pragma unroll
        for (int it = 0; it < 8; ++it) {
            const int rr = arow + it * 16;
            const float4 v = *(const float4*)(Ab + (size_t)rr * 1024 + k0 + acol);
            ushort4 h; h.x = f2bf(v.x); h.y = f2bf(v.y); h.z = f2bf(v.z); h.w = f2bf(v.w);
            *(ushort4*)(&As[rr * LDT + acol]) = h;
        }
#pragma unroll
        for (int it = 0; it < 4; ++it) {
            const int rr = brow + it * 32;
            const uint4 v = *(const uint4*)(Bb + (size_t)rr * 1024 + k0 + bcol);
            *(uint4*)(&Bs[rr * LDT + bcol]) = v;
        }
        __syncthreads();
#pragma unroll
        for (int ks = 0; ks < 2; ++ks) {
            const int ko = ks * 32 + q * 8;
            bf16x8 af[4], bf[4];
#pragma unroll
            for (int tm = 0; tm < 4; ++tm)
                af[tm] = *(const bf16x8*)(&As[(wm * 64 + tm * 16 + r) * LDT + ko]);
#pragma unroll
            for (int tn = 0; tn < 4; ++tn)
                bf[tn] = *(const bf16x8*)(&Bs[(wn * 64 + tn * 16 + r) * LDT + ko]);
#pragma unroll
            for (int tm = 0; tm < 4; ++tm)
#pragma unroll
                for (int tn = 0; tn < 4; ++tn)
                    acc[tm][tn] = __builtin_amdgcn_mfma_f32_16x16x32_bf16(
                        af[tm], bf[tn], acc[tm][tn], 0, 0, 0);
        }
    }
    unsigned short* Tb = Tp + ((size_t)bz << 20);
#pragma unroll
    for (int tm = 0; tm < 4; ++tm)
#pragma unroll
        for (int tn = 0; tn < 4; ++tn) {
            const f32x4 v = acc[tm][tn];
            const int i_e = by * 128 + wm * 64 + tm * 16 + q * 4;  // D row = M = i
            const int p_e = bx * 128 + wn * 64 + tn * 16 + r;      // D col = N = p
            ushort4 h; h.x = f2bf(v[0]); h.y = f2bf(v[1]); h.z = f2bf(v[2]); h.w = f2bf(v[3]);
            *(ushort4*)(Tb + (size_t)p_e * 1024 + i_e) = h;        // transposed store
        }
}

// Stage B: Sigma_out[b][o][p] = sum_i wT[o][i] * T'[b][p][i]  (+ diag_term on diagonal)
__global__ __launch_bounds__(256, 3) void k_gemmB(const unsigned short* __restrict__ wT,
                                                  const unsigned short* __restrict__ Tp,
                                                  const float* __restrict__ dterm,
                                                  float* __restrict__ Cs) {
    __shared__ unsigned short As[128 * LDT];
    __shared__ unsigned short Bs[128 * LDT];
    const int bx = blockIdx.x;   // p-tile
    const int by = blockIdx.y;   // o-tile
    const int bz = blockIdx.z;   // batch
    const int t = threadIdx.x;
    const int lane = t & 63, wave = t >> 6;
    const int wm = wave & 1, wn = wave >> 1;
    const int q = lane >> 4, r = lane & 15;
    const unsigned short* Ab = wT + (size_t)(by * 128) * 1024;
    const unsigned short* Bb = Tp + ((size_t)bz << 20) + (size_t)(bx * 128) * 1024;
    f32x4 acc[4][4];
#pragma unroll
    for (int a = 0; a < 4; ++a)
#pragma unroll
        for (int b2 = 0; b2 < 4; ++b2) acc[a][b2] = (f32x4){0.f, 0.f, 0.f, 0.f};
    const int brow = t >> 3, bcol = (t & 7) * 8;
    for (int kt = 0; kt < 16; ++kt) {
        const int k0 = kt * 64;
        __syncthreads();
#pragma unroll
        for (int it = 0; it < 4; ++it) {
            const int rr = brow + it * 32;
            const uint4 va = *(const uint4*)(Ab + (size_t)rr * 1024 + k0 + bcol);
            *(uint4*)(&As[rr * LDT + bcol]) = va;
            const uint4 vb = *(const uint4*)(Bb + (size_t)rr * 1024 + k0 + bcol);
            *(uint4*)(&Bs[rr * LDT + bcol]) = vb;
        }
        __syncthreads();
#pragma unroll
        for (int ks = 0; ks < 2; ++ks) {
            const int ko = ks * 32 + q * 8;
            bf16x8 af[4], bf[4];
#pragma unroll
            for (int tm = 0; tm < 4; ++tm)
                af[tm] = *(const bf16x8*)(&As[(wm * 64 + tm * 16 + r) * LDT + ko]);
#pragma unroll
            for (int tn = 0; tn < 4; ++tn)
                bf[tn] = *(const bf16x8*)(&Bs[(wn * 64 + tn * 16 + r) * LDT + ko]);
#pragma unroll
            for (int tm = 0; tm < 4; ++tm)
#pragma unroll
                for (int tn = 0; tn < 4; ++tn)
                    acc[tm][tn] = __builtin_amdgcn_mfma_f32_16x16x32_bf16(
                        af[tm], bf[tn], acc[tm][tn], 0, 0, 0);
        }
    }
    float* Cb = Cs + ((size_t)bz << 20);
#pragma unroll
    for (int tm = 0; tm < 4; ++tm)
#pragma unroll
        for (int tn = 0; tn < 4; ++tn) {
            const f32x4 v = acc[tm][tn];
            const int o_b = by * 128 + wm * 64 + tm * 16 + q * 4;
            const int p_e = bx * 128 + wn * 64 + tn * 16 + r;
#pragma unroll
            for (int j = 0; j < 4; ++j) {
                const int o = o_b + j;
                float x = v[j];
                if (o == p_e) x += dterm[bz * 1024 + o];
                Cb[(size_t)o * 1024 + p_e] = x;
            }
        }
}

// ---------------- launch ----------------

extern "C" void kernel_launch(void* const* d_in, const int* in_sizes, int n_in,
                              void* d_out, int out_size, void* d_ws, size_t ws_size,
                              hipStream_t stream) {
    (void)in_sizes; (void)n_in; (void)out_size; (void)ws_size;
    const float* mu_in = (const float*)d_in[0];
    const float* sigma = (const float*)d_in[1];
    const float* w_mu  = (const float*)d_in[2];
    const float* w_sig = (const float*)d_in[3];
    const float* b_mu  = (const float*)d_in[4];
    const float* b_sg  = (const float*)d_in[5];
    float* out = (float*)d_out;

    // workspace layout (needs ~138.6 MB)
    char* ws = (char*)d_ws;
    unsigned short* Tp   = (unsigned short*)(ws + 0x0);          // 128 MB  T' bf16
    float*          wT32 = (float*)(ws + 0x8000000);             // 4 MB
    float*          WSig = (float*)(ws + 0x8400000);             // 4 MB
    unsigned short* wTb  = (unsigned short*)(ws + 0x8800000);    // 2 MB
    float*          dr   = (float*)(ws + 0x8A00000);             // 256 KB
    float*          dt   = (float*)(ws + 0x8A40000);             // 256 KB
    float*          acc  = (float*)(ws + 0x8A80000);             // 64 B

    k_zero<<<1, 64, 0, stream>>>(acc);
    k_transpose<<<dim3(16, 16), 256, 0, stream>>>(w_mu, wT32, wTb, acc);
    k_wsig<<<1024, 256, 0, stream>>>(w_sig, WSig, acc);
    k_gather<<<256, 256, 0, stream>>>(sigma, dr);
    k_small<<<256, 256, 0, stream>>>(mu_in, wT32, WSig, dr, b_mu, b_sg, out, dt);
    k_final<<<1, 256, 0, stream>>>(b_mu, b_sg, acc, out);
    k_gemmA<<<dim3(8, 8, 64), 256, 0, stream>>>(sigma, wTb, Tp);
    k_gemmB<<<dim3(8, 8, 64), 256, 0, stream>>>(wTb, Tp, dt, out + 65536);
}

// Round 2
// 1097.516 us; speedup vs baseline: 1.2240x; 1.2240x over previous
//
#include <hip/hip_runtime.h>
#include <hip/hip_bf16.h>

// Problem: B=64, n=SIZE_IN=1024, m=SIZE_OUT=1024.
// Inputs:  [0] mu_in (64,1024) f32   [1] sigma_in (64,1024,1024) f32
//          [2] w_mu (1024,1024) f32 [i][o]   [3] w_sigma (1024,1024) f32 [o][i]
//          [4] b_mu (1024,1) f32    [5] b_sigma (1024,) f32
// Outputs (flat concat, f32): mu_out (65536) | Sigma_out (67108864) | w_kl | b_kl

typedef short bf16x8 __attribute__((ext_vector_type(8)));
typedef float f32x4  __attribute__((ext_vector_type(4)));
typedef unsigned short u16x8 __attribute__((ext_vector_type(8)));

__device__ __forceinline__ unsigned short f2bf(float f) {
    union { float f; unsigned u; } a; a.f = f;
    unsigned u = a.u;
    u += 0x7fffu + ((u >> 16) & 1u);   // round-to-nearest-even
    return (unsigned short)(u >> 16);
}

__device__ __forceinline__ float softplus_eps(float x) {
    return fmaxf(x, 0.f) + log1pf(expf(-fabsf(x))) + 1e-6f;
}

// async global -> LDS, 16 bytes/lane. LDS dest is wave-uniform base + lane*16;
// our staging index maps thread t -> LDS element t*8 within each 4KB pass, so
// each wave's 64 lanes cover a contiguous 1KB chunk in lane order. [m97 recipe]
__device__ __forceinline__ void gload_lds16(const unsigned short* g, unsigned short* l) {
    __builtin_amdgcn_global_load_lds(
        (const __attribute__((address_space(1))) void*)g,
        (__attribute__((address_space(3))) void*)l, 16, 0, 0);
}

// ---------------- small kernels ----------------

__global__ void k_zero(float* acc) {
    if (threadIdx.x < 16) acc[threadIdx.x] = 0.f;
}

// sigma f32 -> bf16 (into d_out's Sigma region, dead until gemmB overwrites it)
__global__ void k_convert(const float* __restrict__ src, unsigned short* __restrict__ dst) {
    const size_t i = ((size_t)blockIdx.x * 256 + threadIdx.x) * 8;
    const float4 a = *(const float4*)(src + i);
    const float4 b = *(const float4*)(src + i + 4);
    u16x8 h;
    h[0] = f2bf(a.x); h[1] = f2bf(a.y); h[2] = f2bf(a.z); h[3] = f2bf(a.w);
    h[4] = f2bf(b.x); h[5] = f2bf(b.y); h[6] = f2bf(b.z); h[7] = f2bf(b.w);
    *(u16x8*)(dst + i) = h;
}

// transpose w_mu [i][o] -> wT [o][i] (f32 + bf16); accumulate sum(w_mu^2) -> acc[1]
__global__ void k_transpose(const float* __restrict__ wmu, float* __restrict__ wT32,
                            unsigned short* __restrict__ wTb, float* __restrict__ acc) {
    __shared__ float tile[64][65];
    const int bx = blockIdx.x;   // i-tile
    const int by = blockIdx.y;   // o-tile
    const int t = threadIdx.x;
    const int r = t >> 4;            // 0..15
    const int c4 = (t & 15) * 4;     // 0..60
    float s = 0.f;
#pragma unroll
    for (int p = 0; p < 4; ++p) {
        const int row = r + p * 16;
        const float4 v = *(const float4*)(wmu + (size_t)(bx * 64 + row) * 1024 + by * 64 + c4);
        tile[row][c4 + 0] = v.x; tile[row][c4 + 1] = v.y;
        tile[row][c4 + 2] = v.z; tile[row][c4 + 3] = v.w;
        s += v.x * v.x + v.y * v.y + v.z * v.z + v.w * v.w;
    }
    __syncthreads();
#pragma unroll
    for (int p = 0; p < 4; ++p) {
        const int row = r + p * 16;  // local o index
        float4 o;
        o.x = tile[c4 + 0][row]; o.y = tile[c4 + 1][row];
        o.z = tile[c4 + 2][row]; o.w = tile[c4 + 3][row];
        const size_t off = (size_t)(by * 64 + row) * 1024 + bx * 64 + c4;
        *(float4*)(wT32 + off) = o;
        ushort4 h; h.x = f2bf(o.x); h.y = f2bf(o.y); h.z = f2bf(o.z); h.w = f2bf(o.w);
        *(ushort4*)(wTb + off) = h;
    }
#pragma unroll
    for (int off = 32; off; off >>= 1) s += __shfl_down(s, off, 64);
    if ((t & 63) == 0) atomicAdd(acc + 1, s);
}

// W_Sig = softplus(w_sigma)+1e-6 (store f32); accumulate sum(W_Sig)->acc[0], sum(log W_Sig)->acc[2]
__global__ void k_wsig(const float* __restrict__ wsg, float* __restrict__ WSig,
                       float* __restrict__ acc) {
    const int idx = (blockIdx.x * 256 + threadIdx.x) * 4;
    const float4 x = *(const float4*)(wsg + idx);
    float4 w;
    w.x = softplus_eps(x.x); w.y = softplus_eps(x.y);
    w.z = softplus_eps(x.z); w.w = softplus_eps(x.w);
    *(float4*)(WSig + idx) = w;
    float sw = w.x + w.y + w.z + w.w;
    float sl = logf(w.x) + logf(w.y) + logf(w.z) + logf(w.w);
#pragma unroll
    for (int off = 32; off; off >>= 1) {
        sw += __shfl_down(sw, off, 64);
        sl += __shfl_down(sl, off, 64);
    }
    if ((threadIdx.x & 63) == 0) { atomicAdd(acc + 0, sw); atomicAdd(acc + 2, sl); }
}

// faithful replication of the torch .view bug: dr[k*64+q] = sigma.flat[k*65600 + q]
__global__ void k_gather(const float* __restrict__ sig, float* __restrict__ dr) {
    const int tg = blockIdx.x * 256 + threadIdx.x;   // 65536 threads
    const int k = tg >> 6, q = tg & 63;
    dr[tg] = sig[(size_t)k * 65600 + q];
}

// mu_out + diag_term (trW + quad + B_Sig)
__global__ void k_small(const float* __restrict__ mu_in, const float* __restrict__ wT32,
                        const float* __restrict__ WSig, const float* __restrict__ dr,
                        const float* __restrict__ b_mu, const float* __restrict__ b_sig,
                        float* __restrict__ mu_out, float* __restrict__ dterm) {
    __shared__ float mu_s[1024];
    __shared__ float m2_s[1024];
    const int blk = blockIdx.x;
    const int b = blk >> 2;
    const int o0 = (blk & 3) * 256;
    const int t = threadIdx.x;
    const int o = o0 + t;
    for (int j = t; j < 1024; j += 256) {
        const float v = mu_in[b * 1024 + j];
        mu_s[j] = v; m2_s[j] = v * v;
    }
    __syncthreads();
    const int rowTr = b * 16 + (o >> 6);
    const int qq = o & 63;
    const float* wrow = wT32 + (size_t)o * 1024;
    const float* srow = WSig + (size_t)o * 1024;
    const float* trow = WSig + (size_t)rowTr * 1024;
    float am = 0.f, aq = 0.f, at = 0.f;
#pragma unroll 4
    for (int i = 0; i < 1024; i += 4) {
        const float4 wv = *(const float4*)(wrow + i);
        const float4 sv = *(const float4*)(srow + i);
        const float4 tv = *(const float4*)(trow + i);
        const float4 mv = *(const float4*)(&mu_s[i]);
        const float4 m2 = *(const float4*)(&m2_s[i]);
        am += wv.x * mv.x + wv.y * mv.y + wv.z * mv.z + wv.w * mv.w;
        aq += sv.x * m2.x + sv.y * m2.y + sv.z * m2.z + sv.w * m2.w;
        at += tv.x * dr[(i + 0) * 64 + qq] + tv.y * dr[(i + 1) * 64 + qq]
            + tv.z * dr[(i + 2) * 64 + qq] + tv.w * dr[(i + 3) * 64 + qq];
    }
    const float bs = softplus_eps(b_sig[o]);
    dterm[b * 1024 + o] = at + aq + bs;
    mu_out[b * 1024 + o] = am + b_mu[o];
}

// b_kl + finalize w_kl from accumulators
__global__ void k_final(const float* __restrict__ b_mu, const float* __restrict__ b_sig,
                        const float* __restrict__ acc, float* __restrict__ out) {
    __shared__ float red[3][4];
    const int t = threadIdx.x, lane = t & 63, w = t >> 6;
    float s1 = 0.f, s2 = 0.f, s3 = 0.f;
    for (int i = t; i < 1024; i += 256) {
        const float sp = softplus_eps(b_sig[i]);
        s1 += sp; s2 += logf(sp);
        const float bm = b_mu[i]; s3 += bm * bm;
    }
#pragma unroll
    for (int off = 32; off; off >>= 1) {
        s1 += __shfl_down(s1, off, 64);
        s2 += __shfl_down(s2, off, 64);
        s3 += __shfl_down(s3, off, 64);
    }
    if (lane == 0) { red[0][w] = s1; red[1][w] = s2; red[2][w] = s3; }
    __syncthreads();
    if (t == 0) {
        const float S1 = red[0][0] + red[0][1] + red[0][2] + red[0][3];
        const float S2 = red[1][0] + red[1][1] + red[1][2] + red[1][3];
        const float S3 = red[2][0] + red[2][1] + red[2][2] + red[2][3];
        out[67174401] = 0.5f * (S1 + S3 - 1024.f - S2);                      // b_kl
        out[67174400] = 0.5f * (acc[0] + acc[1] - 1048576.f - acc[2]);       // w_kl
    }
}

// ---------------- main GEMMs (m97-style: global_load_lds + unpadded LDS) ----------------
// Stage A: T'[b][p][i] = (Sigma_b @ w_mu)[i][p], bf16, transposed store.
// grid.x = i-tile (sigma-tile owner -> all 8 p-tile siblings share XCD residue),
// grid.y = p-tile, grid.z = batch.
__global__ __launch_bounds__(256) void k_gemmA(const unsigned short* __restrict__ sigb,
                                               const unsigned short* __restrict__ wT,
                                               unsigned short* __restrict__ Tp) {
    __shared__ unsigned short As[128 * 64];
    __shared__ unsigned short Bs[128 * 64];
    const int it_ = blockIdx.x;  // i-tile
    const int pt_ = blockIdx.y;  // p-tile
    const int bz  = blockIdx.z;  // batch
    const int t = threadIdx.x;
    const int lane = t & 63, wave = t >> 6;
    const int wm = wave & 1, wn = wave >> 1;
    const int q = lane >> 4, r = lane & 15;
    const unsigned short* Ab = sigb + ((size_t)bz << 20) + (size_t)(it_ * 128) * 1024;
    const unsigned short* Bb = wT + (size_t)(pt_ * 128) * 1024;
    f32x4 acc[4][4];
#pragma unroll
    for (int a = 0; a < 4; ++a)
#pragma unroll
        for (int b2 = 0; b2 < 4; ++b2) acc[a][b2] = (f32x4){0.f, 0.f, 0.f, 0.f};
    const int srow = t >> 3;          // 0..31
    const int scol = (t & 7) * 8;     // element col within BK=64
    for (int kt = 0; kt < 16; ++kt) {
        const int k0 = kt * 64;
        __syncthreads();
#pragma unroll
        for (int ps = 0; ps < 4; ++ps) {
            const int rr = ps * 32 + srow;
            gload_lds16(Ab + (size_t)rr * 1024 + k0 + scol, &As[ps * 2048 + t * 8]);
            gload_lds16(Bb + (size_t)rr * 1024 + k0 + scol, &Bs[ps * 2048 + t * 8]);
        }
        __syncthreads();
#pragma unroll
        for (int ks = 0; ks < 2; ++ks) {
            const int ko = ks * 32 + q * 8;
            bf16x8 af[4], bf[4];
#pragma unroll
            for (int tm = 0; tm < 4; ++tm)
                af[tm] = *(const bf16x8*)(&As[(wm * 64 + tm * 16 + r) * 64 + ko]);
#pragma unroll
            for (int tn = 0; tn < 4; ++tn)
                bf[tn] = *(const bf16x8*)(&Bs[(wn * 64 + tn * 16 + r) * 64 + ko]);
#pragma unroll
            for (int tm = 0; tm < 4; ++tm)
#pragma unroll
                for (int tn = 0; tn < 4; ++tn)
                    acc[tm][tn] = __builtin_amdgcn_mfma_f32_16x16x32_bf16(
                        af[tm], bf[tn], acc[tm][tn], 0, 0, 0);
        }
    }
    unsigned short* Tb = Tp + ((size_t)bz << 20);
#pragma unroll
    for (int tm = 0; tm < 4; ++tm)
#pragma unroll
        for (int tn = 0; tn < 4; ++tn) {
            const f32x4 v = acc[tm][tn];
            const int i_e = it_ * 128 + wm * 64 + tm * 16 + q * 4;  // D row = M = i
            const int p_e = pt_ * 128 + wn * 64 + tn * 16 + r;      // D col = N = p
            ushort4 h; h.x = f2bf(v[0]); h.y = f2bf(v[1]); h.z = f2bf(v[2]); h.w = f2bf(v[3]);
            *(ushort4*)(Tb + (size_t)p_e * 1024 + i_e) = h;         // transposed store
        }
}

// Stage B: Sigma_out[b][o][p] = sum_i wT[o][i] * T'[b][p][i]  (+ diag_term on diagonal)
// grid.x = p-tile (Tp-tile owner), grid.y = o-tile, grid.z = batch.
__global__ __launch_bounds__(256) void k_gemmB(const unsigned short* __restrict__ wT,
                                               const unsigned short* __restrict__ Tp,
                                               const float* __restrict__ dterm,
                                               float* __restrict__ Cs) {
    __shared__ unsigned short As[128 * 64];
    __shared__ unsigned short Bs[128 * 64];
    const int pt_ = blockIdx.x;  // p-tile
    const int ot_ = blockIdx.y;  // o-tile
    const int bz  = blockIdx.z;  // batch
    const int t = threadIdx.x;
    const int lane = t & 63, wave = t >> 6;
    const int wm = wave & 1, wn = wave >> 1;
    const int q = lane >> 4, r = lane & 15;
    const unsigned short* Ab = wT + (size_t)(ot_ * 128) * 1024;
    const unsigned short* Bb = Tp + ((size_t)bz << 20) + (size_t)(pt_ * 128) * 1024;
    f32x4 acc[4][4];
#pragma unroll
    for (int a = 0; a < 4; ++a)
#pragma unroll
        for (int b2 = 0; b2 < 4; ++b2) acc[a][b2] = (f32x4){0.f, 0.f, 0.f, 0.f};
    const int srow = t >> 3;
    const int scol = (t & 7) * 8;
    for (int kt = 0; kt < 16; ++kt) {
        const int k0 = kt * 64;
        __syncthreads();
#pragma unroll
        for (int ps = 0; ps < 4; ++ps) {
            const int rr = ps * 32 + srow;
            gload_lds16(Ab + (size_t)rr * 1024 + k0 + scol, &As[ps * 2048 + t * 8]);
            gload_lds16(Bb + (size_t)rr * 1024 + k0 + scol, &Bs[ps * 2048 + t * 8]);
        }
        __syncthreads();
#pragma unroll
        for (int ks = 0; ks < 2; ++ks) {
            const int ko = ks * 32 + q * 8;
            bf16x8 af[4], bf[4];
#pragma unroll
            for (int tm = 0; tm < 4; ++tm)
                af[tm] = *(const bf16x8*)(&As[(wm * 64 + tm * 16 + r) * 64 + ko]);
#pragma unroll
            for (int tn = 0; tn < 4; ++tn)
                bf[tn] = *(const bf16x8*)(&Bs[(wn * 64 + tn * 16 + r) * 64 + ko]);
#pragma unroll
            for (int tm = 0; tm < 4; ++tm)
#pragma unroll
                for (int tn = 0; tn < 4; ++tn)
                    acc[tm][tn] = __builtin_amdgcn_mfma_f32_16x16x32_bf16(
                        af[tm], bf[tn], acc[tm][tn], 0, 0, 0);
        }
    }
    float* Cb = Cs + ((size_t)bz << 20);
#pragma unroll
    for (int tm = 0; tm < 4; ++tm)
#pragma unroll
        for (int tn = 0; tn < 4; ++tn) {
            const f32x4 v = acc[tm][tn];
            const int o_b = ot_ * 128 + wm * 64 + tm * 16 + q * 4;
            const int p_e = pt_ * 128 + wn * 64 + tn * 16 + r;
#pragma unroll
            for (int j = 0; j < 4; ++j) {
                const int o = o_b + j;
                float x = v[j];
                if (o == p_e) x += dterm[bz * 1024 + o];
                Cb[(size_t)o * 1024 + p_e] = x;
            }
        }
}

// ---------------- launch ----------------

extern "C" void kernel_launch(void* const* d_in, const int* in_sizes, int n_in,
                              void* d_out, int out_size, void* d_ws, size_t ws_size,
                              hipStream_t stream) {
    (void)in_sizes; (void)n_in; (void)out_size; (void)ws_size;
    const float* mu_in = (const float*)d_in[0];
    const float* sigma = (const float*)d_in[1];
    const float* w_mu  = (const float*)d_in[2];
    const float* w_sig = (const float*)d_in[3];
    const float* b_mu  = (const float*)d_in[4];
    const float* b_sg  = (const float*)d_in[5];
    float* out = (float*)d_out;

    // workspace layout (~138.6 MB)
    char* ws = (char*)d_ws;
    unsigned short* Tp   = (unsigned short*)(ws + 0x0);          // 128 MB  T' bf16
    float*          wT32 = (float*)(ws + 0x8000000);             // 4 MB
    float*          WSig = (float*)(ws + 0x8400000);             // 4 MB
    unsigned short* wTb  = (unsigned short*)(ws + 0x8800000);    // 2 MB
    float*          dr   = (float*)(ws + 0x8A00000);             // 256 KB
    float*          dt   = (float*)(ws + 0x8A40000);             // 256 KB
    float*          acc  = (float*)(ws + 0x8A80000);             // 64 B

    // bf16 sigma lives in d_out's Sigma region (dead until k_gemmB overwrites it)
    unsigned short* sigb = (unsigned short*)(out + 65536);       // 128 MB of the 256 MB region

    k_zero<<<1, 64, 0, stream>>>(acc);
    k_convert<<<32768, 256, 0, stream>>>(sigma, sigb);
    k_transpose<<<dim3(16, 16), 256, 0, stream>>>(w_mu, wT32, wTb, acc);
    k_wsig<<<1024, 256, 0, stream>>>(w_sig, WSig, acc);
    k_gather<<<256, 256, 0, stream>>>(sigma, dr);
    k_small<<<256, 256, 0, stream>>>(mu_in, wT32, WSig, dr, b_mu, b_sg, out, dt);
    k_final<<<1, 256, 0, stream>>>(b_mu, b_sg, acc, out);
    k_gemmA<<<dim3(8, 8, 64), 256, 0, stream>>>(sigb, wTb, Tp);
    k_gemmB<<<dim3(8, 8, 64), 256, 0, stream>>>(wTb, Tp, dt, out + 65536);
}